// Round 1
// baseline (444.911 us; speedup 1.0000x reference)
//
#include <hip/hip_runtime.h>
#include <stdint.h>

#define B_  4
#define S_  2048
#define H_  1024
#define NH_ 16
#define DK_ 64
#define M_  (B_*S_)   // 8192

typedef unsigned short u16;
typedef __attribute__((ext_vector_type(8))) short bfrag;   // 8 x bf16 (4 VGPRs)
typedef __attribute__((ext_vector_type(4))) float facc;    // 4 x f32 accumulator

__device__ __forceinline__ u16 f2bf(float f) {
  uint32_t u = __float_as_uint(f);
  return (u16)((u + 0x7fffu + ((u >> 16) & 1u)) >> 16);    // RNE
}

// ---------------- f32 -> bf16 convert (vectorized) ----------------
__global__ void cvt_kernel(const float* __restrict__ in, u16* __restrict__ out, int n4) {
  int i = blockIdx.x * blockDim.x + threadIdx.x;
  int stride = gridDim.x * blockDim.x;
  for (; i < n4; i += stride) {
    float4 v = reinterpret_cast<const float4*>(in)[i];
    ushort4 o;
    o.x = f2bf(v.x); o.y = f2bf(v.y); o.z = f2bf(v.z); o.w = f2bf(v.w);
    reinterpret_cast<ushort4*>(out)[i] = o;
  }
}

// ---------------- mask int32 -> packed bits ----------------
__global__ void pack_mask_kernel(const int* __restrict__ m, uint32_t* __restrict__ bits, int nwords) {
  int w = blockIdx.x * blockDim.x + threadIdx.x;
  if (w >= nwords) return;
  const int4* p = reinterpret_cast<const int4*>(m) + (size_t)w * 8;
  uint32_t word = 0;
  #pragma unroll
  for (int i = 0; i < 8; i++) {
    int4 v = p[i];
    word |= (uint32_t)(v.x != 0) << (i*4);
    word |= (uint32_t)(v.y != 0) << (i*4+1);
    word |= (uint32_t)(v.z != 0) << (i*4+2);
    word |= (uint32_t)(v.w != 0) << (i*4+3);
  }
  bits[w] = word;
}

// ---------------- GEMM: C = A @ B^T (+bias) ----------------
// A[M][K] bf16, B[N][K] bf16 (weights are stored [n][k] which is exactly B^T input)
// MODE 0: bf16 out to head layout [B][NH][S][DK]; MODE 1: f32 out row-major [M][N]
#define GLD16(gsrc, ldst) \
  __builtin_amdgcn_global_load_lds((const __attribute__((address_space(1))) void*)(gsrc), \
                                   (__attribute__((address_space(3))) void*)(ldst), 16, 0, 0)

template<int MODE>
__global__ __launch_bounds__(256) void gemm_bt(const u16* __restrict__ A, const u16* __restrict__ Bm,
                                               const float* __restrict__ bias, void* __restrict__ Cout) {
  constexpr int K = H_, N = H_;
  __shared__ __align__(16) u16 As[128*32];
  __shared__ __align__(16) u16 Bs[128*32];
  const int tid = threadIdx.x;
  const int lane = tid & 63, wave = tid >> 6;
  const int lo = lane & 15, hi = lane >> 4;
  const int wr = wave >> 1, wc = wave & 1;
  const int m0 = blockIdx.x * 128, n0 = blockIdx.y * 128;
  facc acc[4][4] = {};

  for (int k0 = 0; k0 < K; k0 += 32) {
    const u16* Ab = A + (size_t)m0 * K + k0;
    const u16* Bb = Bm + (size_t)n0 * K + k0;
    #pragma unroll
    for (int i = 0; i < 2; i++) {
      int idx = i*256 + tid;          // 0..511, 16B chunk index; row=idx>>2, quarter=idx&3
      int row = idx >> 2, q = idx & 3;
      char* la = (char*)As + i*4096 + wave*1024;   // wave-uniform LDS base; HW adds lane*16
      char* lb = (char*)Bs + i*4096 + wave*1024;
      GLD16(Ab + (size_t)row*K + q*8, la);
      GLD16(Bb + (size_t)row*K + q*8, lb);
    }
    __syncthreads();
    bfrag af[4], bfv[4];
    #pragma unroll
    for (int t = 0; t < 4; t++) {
      af[t]  = *reinterpret_cast<const bfrag*>(&As[(wr*64 + t*16 + lo)*32 + hi*8]);
      bfv[t] = *reinterpret_cast<const bfrag*>(&Bs[(wc*64 + t*16 + lo)*32 + hi*8]);
    }
    #pragma unroll
    for (int mt = 0; mt < 4; mt++)
      #pragma unroll
      for (int nt = 0; nt < 4; nt++)
        acc[mt][nt] = __builtin_amdgcn_mfma_f32_16x16x32_bf16(af[mt], bfv[nt], acc[mt][nt], 0, 0, 0);
    __syncthreads();
  }

  if (MODE == 0) {
    u16* o = reinterpret_cast<u16*>(Cout);
    #pragma unroll
    for (int nt = 0; nt < 4; nt++) {
      int n = n0 + wc*64 + nt*16 + lo;
      float bv = bias[n];
      int hh = n >> 6, d = n & 63;
      #pragma unroll
      for (int mt = 0; mt < 4; mt++) {
        #pragma unroll
        for (int r = 0; r < 4; r++) {
          int m = m0 + wr*64 + mt*16 + hi*4 + r;   // C/D row = (lane>>4)*4 + reg
          int bb = m >> 11, s = m & (S_ - 1);
          o[(((size_t)bb*NH_ + hh)*S_ + s)*DK_ + d] = f2bf(acc[mt][nt][r] + bv);
        }
      }
    }
  } else {
    float* o = reinterpret_cast<float*>(Cout);
    #pragma unroll
    for (int nt = 0; nt < 4; nt++) {
      int n = n0 + wc*64 + nt*16 + lo;
      float bv = bias[n];
      #pragma unroll
      for (int mt = 0; mt < 4; mt++) {
        #pragma unroll
        for (int r = 0; r < 4; r++) {
          int m = m0 + wr*64 + mt*16 + hi*4 + r;
          o[(size_t)m*N + n] = acc[mt][nt][r] + bv;
        }
      }
    }
  }
}

// ---------------- V transpose: [bh][s][d] -> [bh][d][s] ----------------
__global__ __launch_bounds__(256) void transpose_v(const u16* __restrict__ vh, u16* __restrict__ vt) {
  __shared__ __align__(16) u16 t[64][72];
  const int tid = threadIdx.x;
  const int bh = blockIdx.y;
  const int s0 = blockIdx.x * 64;
  const u16* src = vh + ((size_t)bh * S_ + s0) * 64;
  #pragma unroll
  for (int i = 0; i < 2; i++) {
    int idx = i*256 + tid;           // 512 chunks of 8 elems
    int r = idx >> 3, c8 = idx & 7;
    *reinterpret_cast<bfrag*>(&t[r][c8*8]) = *reinterpret_cast<const bfrag*>(src + idx*8);
  }
  __syncthreads();
  u16* dst = vt + (size_t)bh * 64 * S_ + s0;
  #pragma unroll
  for (int i = 0; i < 2; i++) {
    int idx = i*256 + tid;
    int d = idx >> 3, c8 = idx & 7;
    bfrag ov;
    #pragma unroll
    for (int j = 0; j < 8; j++) ov[j] = (short)t[c8*8 + j][d];
    *reinterpret_cast<bfrag*>(dst + (size_t)d * S_ + c8*8) = ov;
  }
}

// ---------------- Flash attention ----------------
// Qh,Kh: [bh][s][64] bf16; Vt: [bh][64][s] bf16; mbits: [b][s][64 words]; xout: [b*S][H] bf16
__global__ __launch_bounds__(256) void attn_kernel(const u16* __restrict__ Qh, const u16* __restrict__ Kh,
                                                   const u16* __restrict__ Vt, const uint32_t* __restrict__ mbits,
                                                   u16* __restrict__ xout) {
  __shared__ __align__(16) u16 Ks[64][72];
  __shared__ __align__(16) u16 Vs[64][72];
  __shared__ __align__(16) u16 Ps[64][72];
  __shared__ uint32_t Ms[64][65];
  const int tid = threadIdx.x;
  const int lane = tid & 63, wave = tid >> 6;
  const int lo = lane & 15, hi = lane >> 4;
  const int bh = blockIdx.y;
  const int b = bh >> 4;            // NH=16
  const int h = bh & 15;
  const int q0 = blockIdx.x * 64;
  const size_t bhS = (size_t)bh * S_;

  // Q fragments for this wave's 16 rows (A-operand: row=lane&15, k=(lane>>4)*8)
  bfrag qa0, qa1;
  {
    const u16* qrow = Qh + (bhS + q0 + wave*16 + lo) * DK_;
    qa0 = *reinterpret_cast<const bfrag*>(qrow + hi*8);
    qa1 = *reinterpret_cast<const bfrag*>(qrow + 32 + hi*8);
  }
  // stage mask bits for this q-tile: 64 rows x 64 words
  #pragma unroll
  for (int i = 0; i < 16; i++) {
    int idx = i*256 + tid;
    int r = idx >> 6, w = idx & 63;
    Ms[r][w] = mbits[((size_t)b * S_ + q0 + r) * 64 + w];
  }

  float m_run[4], l_run[4];
  facc accO[4];
  #pragma unroll
  for (int r = 0; r < 4; r++) { m_run[r] = -1e30f; l_run[r] = 0.f; accO[r] = facc{0.f,0.f,0.f,0.f}; }

  for (int c = 0; c < 32; c++) {
    const int k0 = c * 64;
    __syncthreads();  // protect LDS from previous iteration's readers (also publishes Ms on c==0)
    {
      const u16* kb = Kh + (bhS + k0) * DK_;             // 64x64 contiguous
      const u16* vb = Vt + (size_t)bh * 64 * S_ + k0;    // 64 rows, stride S
      #pragma unroll
      for (int i = 0; i < 2; i++) {
        int idx = i*256 + tid;
        int r = idx >> 3, c8 = idx & 7;
        *reinterpret_cast<bfrag*>(&Ks[r][c8*8]) = *reinterpret_cast<const bfrag*>(kb + idx*8);
        *reinterpret_cast<bfrag*>(&Vs[r][c8*8]) = *reinterpret_cast<const bfrag*>(vb + (size_t)r*S_ + c8*8);
      }
    }
    __syncthreads();

    // ---- QK^T: 4 k-subtiles of 16, D[row=q][col=k_local] ----
    facc sacc[4];
    #pragma unroll
    for (int tk = 0; tk < 4; tk++) {
      facc a = facc{0.f,0.f,0.f,0.f};
      bfrag kf0 = *reinterpret_cast<const bfrag*>(&Ks[tk*16 + lo][hi*8]);
      bfrag kf1 = *reinterpret_cast<const bfrag*>(&Ks[tk*16 + lo][32 + hi*8]);
      a = __builtin_amdgcn_mfma_f32_16x16x32_bf16(qa0, kf0, a, 0, 0, 0);
      a = __builtin_amdgcn_mfma_f32_16x16x32_bf16(qa1, kf1, a, 0, 0, 0);
      sacc[tk] = a;
    }

    // ---- mask + online softmax ----
    uint32_t mw0[4], mw1[4];
    #pragma unroll
    for (int r = 0; r < 4; r++) {
      int row = wave*16 + hi*4 + r;
      mw0[r] = Ms[row][c*2];
      mw1[r] = Ms[row][c*2 + 1];
    }
    float sv[4][4];     // [tk][r]
    float mchunk[4];
    #pragma unroll
    for (int r = 0; r < 4; r++) mchunk[r] = -1e30f;
    #pragma unroll
    for (int tk = 0; tk < 4; tk++) {
      int kin = tk*16 + lo;          // 0..63 within chunk
      #pragma unroll
      for (int r = 0; r < 4; r++) {
        uint32_t w = (tk < 2) ? mw0[r] : mw1[r];
        bool msk = (w >> (kin & 31)) & 1u;
        float s = sacc[tk][r] * 0.125f;          // 1/sqrt(64)
        sv[tk][r] = msk ? -1e30f : s;
        mchunk[r] = fmaxf(mchunk[r], sv[tk][r]);
      }
    }
    #pragma unroll
    for (int r = 0; r < 4; r++) {
      float m = mchunk[r];
      m = fmaxf(m, __shfl_xor(m, 1));
      m = fmaxf(m, __shfl_xor(m, 2));
      m = fmaxf(m, __shfl_xor(m, 4));
      m = fmaxf(m, __shfl_xor(m, 8));
      float mnew = fmaxf(m_run[r], m);
      float alpha = __expf(m_run[r] - mnew);
      m_run[r] = mnew;
      l_run[r] *= alpha;
      #pragma unroll
      for (int dn = 0; dn < 4; dn++) accO[dn][r] *= alpha;
      float lsum = 0.f;
      #pragma unroll
      for (int tk = 0; tk < 4; tk++) {
        float p = (sv[tk][r] <= -1e29f) ? 0.f : __expf(sv[tk][r] - mnew);  // masked -> exactly 0
        sv[tk][r] = p;
        lsum += p;
      }
      lsum += __shfl_xor(lsum, 1);
      lsum += __shfl_xor(lsum, 2);
      lsum += __shfl_xor(lsum, 4);
      lsum += __shfl_xor(lsum, 8);
      l_run[r] += lsum;
    }

    // ---- P -> LDS (bf16), wave-local rows ----
    #pragma unroll
    for (int tk = 0; tk < 4; tk++)
      #pragma unroll
      for (int r = 0; r < 4; r++)
        Ps[wave*16 + hi*4 + r][tk*16 + lo] = f2bf(sv[tk][r]);
    __syncthreads();

    // ---- PV: accO[dn] += P(16x64) @ V^T tiles ----
    #pragma unroll
    for (int ks = 0; ks < 2; ks++) {
      bfrag pa = *reinterpret_cast<const bfrag*>(&Ps[wave*16 + lo][ks*32 + hi*8]);
      #pragma unroll
      for (int dn = 0; dn < 4; dn++) {
        bfrag vf = *reinterpret_cast<const bfrag*>(&Vs[dn*16 + lo][ks*32 + hi*8]);
        accO[dn] = __builtin_amdgcn_mfma_f32_16x16x32_bf16(pa, vf, accO[dn], 0, 0, 0);
      }
    }
  }

  // ---- finalize: divide by l, write x in [b*S][H] layout for the output GEMM ----
  #pragma unroll
  for (int r = 0; r < 4; r++) {
    float inv = (l_run[r] > 0.f) ? (1.f / l_run[r]) : 0.f;
    int q = q0 + wave*16 + hi*4 + r;
    u16* orow = xout + ((size_t)b * S_ + q) * H_ + h * DK_;
    #pragma unroll
    for (int dn = 0; dn < 4; dn++)
      orow[dn*16 + lo] = f2bf(accO[dn][r] * inv);
  }
}

// ---------------- launch ----------------
extern "C" void kernel_launch(void* const* d_in, const int* in_sizes, int n_in,
                              void* d_out, int out_size, void* d_ws, size_t ws_size,
                              hipStream_t stream) {
  const float* query = (const float*)d_in[0];
  const float* key_  = (const float*)d_in[1];
  const float* value = (const float*)d_in[2];
  const int*   mask  = (const int*)d_in[3];
  const float* Wq = (const float*)d_in[4];
  const float* bq = (const float*)d_in[5];
  const float* Wk = (const float*)d_in[6];
  const float* bk = (const float*)d_in[7];
  const float* Wv = (const float*)d_in[8];
  const float* bv = (const float*)d_in[9];
  const float* Wo = (const float*)d_in[10];
  const float* bo = (const float*)d_in[11];
  float* out = (float*)d_out;

  char* ws = (char*)d_ws;
  const size_t MB = 1024 * 1024;
  u16* q_act = (u16*)(ws + 0*MB);     // [8192][1024] bf16, 16 MiB
  u16* k_act = (u16*)(ws + 16*MB);
  u16* v_act = (u16*)(ws + 32*MB);
  u16* wq_b  = (u16*)(ws + 48*MB);    // [1024][1024] bf16, 2 MiB each
  u16* wk_b  = (u16*)(ws + 50*MB);
  u16* wv_b  = (u16*)(ws + 52*MB);
  u16* wo_b  = (u16*)(ws + 54*MB);
  u16* qh    = (u16*)(ws + 56*MB);    // [B][NH][S][DK] 16 MiB
  u16* kh    = (u16*)(ws + 72*MB);
  u16* vh    = (u16*)(ws + 88*MB);
  u16* vt    = (u16*)(ws + 104*MB);   // [B][NH][DK][S]
  u16* xb    = (u16*)(ws + 120*MB);   // [B*S][H] attention out
  uint32_t* mbits = (uint32_t*)(ws + 136*MB);  // 2 MiB

  const int nact4 = M_ * H_ / 4;
  cvt_kernel<<<2048, 256, 0, stream>>>(query, q_act, nact4);
  cvt_kernel<<<2048, 256, 0, stream>>>(key_,  k_act, nact4);
  cvt_kernel<<<2048, 256, 0, stream>>>(value, v_act, nact4);
  const int nw4 = H_ * H_ / 4;
  cvt_kernel<<<1024, 256, 0, stream>>>(Wq, wq_b, nw4);
  cvt_kernel<<<1024, 256, 0, stream>>>(Wk, wk_b, nw4);
  cvt_kernel<<<1024, 256, 0, stream>>>(Wv, wv_b, nw4);
  cvt_kernel<<<1024, 256, 0, stream>>>(Wo, wo_b, nw4);
  const int nwords = B_ * S_ * S_ / 32;  // 524288
  pack_mask_kernel<<<nwords/256, 256, 0, stream>>>(mask, mbits, nwords);

  dim3 gg(M_/128, H_/128);  // 64 x 8
  gemm_bt<0><<<gg, 256, 0, stream>>>(q_act, wq_b, bq, qh);
  gemm_bt<0><<<gg, 256, 0, stream>>>(k_act, wk_b, bk, kh);
  gemm_bt<0><<<gg, 256, 0, stream>>>(v_act, wv_b, bv, vh);
  transpose_v<<<dim3(S_/64, B_*NH_), 256, 0, stream>>>(vh, vt);
  attn_kernel<<<dim3(S_/64, B_*NH_), 256, 0, stream>>>(qh, kh, vt, mbits, xb);
  gemm_bt<1><<<gg, 256, 0, stream>>>(xb, wo_b, bo, out);
}

// Round 2
// 313.665 us; speedup vs baseline: 1.4184x; 1.4184x over previous
//
#include <hip/hip_runtime.h>
#include <hip/hip_bf16.h>
#include <stdint.h>

#define B_  4
#define S_  2048
#define H_  1024
#define NH_ 16
#define DK_ 64
#define M_  (B_*S_)   // 8192

typedef unsigned short u16;
typedef __attribute__((ext_vector_type(8))) short bfrag;   // 8 x bf16 (4 VGPRs)
typedef __attribute__((ext_vector_type(4))) float facc;    // 4 x f32 accumulator

__device__ __forceinline__ u16 f2bf(float f) {
  uint32_t u = __float_as_uint(f);
  return (u16)((u + 0x7fffu + ((u >> 16) & 1u)) >> 16);    // RNE
}

__device__ __forceinline__ uint32_t pack_bf16x2(float a, float b) {
  __hip_bfloat162 h = __float22bfloat162_rn(float2{a, b});
  union { __hip_bfloat162 h; uint32_t u; } cv; cv.h = h; return cv.u;
}

// ---------------- f32 -> bf16 convert (vectorized, optional scale) ----------------
__global__ void cvt_kernel(const float* __restrict__ in, u16* __restrict__ out, int n4, float scale) {
  int i = blockIdx.x * blockDim.x + threadIdx.x;
  int stride = gridDim.x * blockDim.x;
  for (; i < n4; i += stride) {
    float4 v = reinterpret_cast<const float4*>(in)[i];
    ushort4 o;
    o.x = f2bf(v.x * scale); o.y = f2bf(v.y * scale);
    o.z = f2bf(v.z * scale); o.w = f2bf(v.w * scale);
    reinterpret_cast<ushort4*>(out)[i] = o;
  }
}

// ---------------- mask int32 -> packed bits ----------------
__global__ void pack_mask_kernel(const int* __restrict__ m, uint32_t* __restrict__ bits, int nwords) {
  int w = blockIdx.x * blockDim.x + threadIdx.x;
  if (w >= nwords) return;
  const int4* p = reinterpret_cast<const int4*>(m) + (size_t)w * 8;
  uint32_t word = 0;
  #pragma unroll
  for (int i = 0; i < 8; i++) {
    int4 v = p[i];
    word |= (uint32_t)(v.x != 0) << (i*4);
    word |= (uint32_t)(v.y != 0) << (i*4+1);
    word |= (uint32_t)(v.z != 0) << (i*4+2);
    word |= (uint32_t)(v.w != 0) << (i*4+3);
  }
  bits[w] = word;
}

// ---------------- GEMM: C = A @ B^T (+bias*bscale) ----------------
#define GLD16(gsrc, ldst) \
  __builtin_amdgcn_global_load_lds((const __attribute__((address_space(1))) void*)(gsrc), \
                                   (__attribute__((address_space(3))) void*)(ldst), 16, 0, 0)

template<int MODE>
__global__ __launch_bounds__(256) void gemm_bt(const u16* __restrict__ A, const u16* __restrict__ Bm,
                                               const float* __restrict__ bias, float bscale,
                                               void* __restrict__ Cout) {
  constexpr int K = H_, N = H_;
  __shared__ __align__(16) u16 As[128*32];
  __shared__ __align__(16) u16 Bs[128*32];
  const int tid = threadIdx.x;
  const int lane = tid & 63, wave = tid >> 6;
  const int lo = lane & 15, hi = lane >> 4;
  const int wr = wave >> 1, wc = wave & 1;
  const int m0 = blockIdx.x * 128, n0 = blockIdx.y * 128;
  facc acc[4][4] = {};

  for (int k0 = 0; k0 < K; k0 += 32) {
    const u16* Ab = A + (size_t)m0 * K + k0;
    const u16* Bb = Bm + (size_t)n0 * K + k0;
    #pragma unroll
    for (int i = 0; i < 2; i++) {
      int idx = i*256 + tid;
      int row = idx >> 2, q = idx & 3;
      char* la = (char*)As + i*4096 + wave*1024;
      char* lb = (char*)Bs + i*4096 + wave*1024;
      GLD16(Ab + (size_t)row*K + q*8, la);
      GLD16(Bb + (size_t)row*K + q*8, lb);
    }
    __syncthreads();
    bfrag af[4], bfv[4];
    #pragma unroll
    for (int t = 0; t < 4; t++) {
      af[t]  = *reinterpret_cast<const bfrag*>(&As[(wr*64 + t*16 + lo)*32 + hi*8]);
      bfv[t] = *reinterpret_cast<const bfrag*>(&Bs[(wc*64 + t*16 + lo)*32 + hi*8]);
    }
    #pragma unroll
    for (int mt = 0; mt < 4; mt++)
      #pragma unroll
      for (int nt = 0; nt < 4; nt++)
        acc[mt][nt] = __builtin_amdgcn_mfma_f32_16x16x32_bf16(af[mt], bfv[nt], acc[mt][nt], 0, 0, 0);
    __syncthreads();
  }

  if (MODE == 0) {
    u16* o = reinterpret_cast<u16*>(Cout);
    #pragma unroll
    for (int nt = 0; nt < 4; nt++) {
      int n = n0 + wc*64 + nt*16 + lo;
      float bv = bias[n] * bscale;
      int hh = n >> 6, d = n & 63;
      #pragma unroll
      for (int mt = 0; mt < 4; mt++) {
        #pragma unroll
        for (int r = 0; r < 4; r++) {
          int m = m0 + wr*64 + mt*16 + hi*4 + r;
          int bb = m >> 11, s = m & (S_ - 1);
          o[(((size_t)bb*NH_ + hh)*S_ + s)*DK_ + d] = f2bf(acc[mt][nt][r] + bv);
        }
      }
    }
  } else {
    float* o = reinterpret_cast<float*>(Cout);
    #pragma unroll
    for (int nt = 0; nt < 4; nt++) {
      int n = n0 + wc*64 + nt*16 + lo;
      float bv = bias[n] * bscale;
      #pragma unroll
      for (int mt = 0; mt < 4; mt++) {
        #pragma unroll
        for (int r = 0; r < 4; r++) {
          int m = m0 + wr*64 + mt*16 + hi*4 + r;
          o[(size_t)m*N + n] = acc[mt][nt][r] + bv;
        }
      }
    }
  }
}

// ---------------- V transpose: [bh][s][d] -> [bh][d][s] ----------------
__global__ __launch_bounds__(256) void transpose_v(const u16* __restrict__ vh, u16* __restrict__ vt) {
  __shared__ __align__(16) u16 t[64][72];
  const int tid = threadIdx.x;
  const int bh = blockIdx.y;
  const int s0 = blockIdx.x * 64;
  const u16* src = vh + ((size_t)bh * S_ + s0) * 64;
  #pragma unroll
  for (int i = 0; i < 2; i++) {
    int idx = i*256 + tid;
    int r = idx >> 3, c8 = idx & 7;
    *reinterpret_cast<bfrag*>(&t[r][c8*8]) = *reinterpret_cast<const bfrag*>(src + idx*8);
  }
  __syncthreads();
  u16* dst = vt + (size_t)bh * 64 * S_ + s0;
  #pragma unroll
  for (int i = 0; i < 2; i++) {
    int idx = i*256 + tid;
    int d = idx >> 3, c8 = idx & 7;
    bfrag ov;
    #pragma unroll
    for (int j = 0; j < 8; j++) ov[j] = (short)t[c8*8 + j][d];
    *reinterpret_cast<bfrag*>(dst + (size_t)d * S_ + c8*8) = ov;
  }
}

// ---------------- Flash attention v2 ----------------
// Swapped QK^T (lane-local softmax rows), XOR-swizzled LDS, dbuf K/V via global_load_lds,
// 1 barrier/chunk. Qh is pre-scaled by 0.125*log2(e) (folded into Wq/bq), so exp -> exp2.
// Qh,Kh: [bh][s][64] bf16; Vt: [bh][64][s] bf16; mbits: [b][s][64 words]; xout: [b*S][H] bf16
__global__ __launch_bounds__(256, 4) void attn_kernel(const u16* __restrict__ Qh, const u16* __restrict__ Kh,
                                                      const u16* __restrict__ Vt, const uint32_t* __restrict__ mbits,
                                                      u16* __restrict__ xout) {
  __shared__ __align__(16) u16 Ks[2][64*64];   // 8 KiB each, XOR-swizzled rows of 128 B
  __shared__ __align__(16) u16 Vs[2][64*64];
  __shared__ __align__(16) u16 Ps[64*64];
  const int tid = threadIdx.x;
  const int lane = tid & 63, wave = tid >> 6;
  const int lo = lane & 15, hi = lane >> 4;
  const int bh = blockIdx.y, b = bh >> 4, h = bh & 15;
  const int q0 = blockIdx.x * 64;
  const size_t bhS = (size_t)bh * S_;

  // Q fragments as B-operand (row=q=lo within wave's 16 rows, k=hi*8..)
  bfrag qf0, qf1;
  {
    const u16* qrow = Qh + (bhS + q0 + wave*16 + lo) * DK_;
    qf0 = *reinterpret_cast<const bfrag*>(qrow + hi*8);
    qf1 = *reinterpret_cast<const bfrag*>(qrow + 32 + hi*8);
  }
  // per-lane mask row pointer (q = q0 + wave*16 + lo), 2 words per chunk
  const uint32_t* mrow = mbits + ((size_t)b * S_ + q0 + wave*16 + lo) * 64;

  // staging source addressing (pre-swizzled so linear global_load_lds lands swizzled)
  const int srow = wave*8 + (lane >> 3);                 // + i*32
  const int scol = ((lane & 7) ^ (lane >> 3)) * 16;      // bytes, XOR pre-applied
  const char* ksrc = (const char*)(Kh + bhS * DK_) + (size_t)srow * 128 + scol;
  const char* vsrc = (const char*)(Vt + (size_t)bh * DK_ * S_) + (size_t)srow * (S_*2) + scol;

#define STAGE(buf, c) { \
    char* kl = (char*)Ks[buf] + wave*1024; \
    char* vl = (char*)Vs[buf] + wave*1024; \
    GLD16(ksrc + (size_t)(c)*8192,          kl); \
    GLD16(ksrc + (size_t)(c)*8192 + 4096,   kl + 4096); \
    GLD16(vsrc + (size_t)(c)*128,           vl); \
    GLD16(vsrc + (size_t)(c)*128 + 131072,  vl + 4096); \
  }

  float m_run = -1e30f, l_run = 0.f;
  facc accO[4];
  #pragma unroll
  for (int dn = 0; dn < 4; dn++) accO[dn] = facc{0.f, 0.f, 0.f, 0.f};

  const int prow = wave*16 + lo;                 // this lane's P row (q-local)
  const int psw = (lo & 7) << 4;                 // XOR key for row prow (prow&7 == lo&7)
  char* pbase = (char*)Ps + prow * 128;

  STAGE(0, 0);
  __syncthreads();

  for (int c = 0; c < 32; c++) {
    const int cur = c & 1;
    if (c + 1 < 32) STAGE(cur ^ 1, c + 1);       // prefetch next chunk (drained at barrier)

    uint2 mw = *reinterpret_cast<const uint2*>(mrow + c*2);

    // ---- QK^T swapped: D[k][q], lane holds q=lo, k = tk*16 + hi*4 + r ----
    facc sacc[4];
    const char* KsB = (const char*)Ks[cur];
    #pragma unroll
    for (int tk = 0; tk < 4; tk++) {
      int row = tk*16 + lo;
      int sw = (lo & 7) << 4;
      bfrag kf0 = *reinterpret_cast<const bfrag*>(KsB + row*128 + ((hi*16) ^ sw));
      bfrag kf1 = *reinterpret_cast<const bfrag*>(KsB + row*128 + ((64 + hi*16) ^ sw));
      facc a = facc{0.f, 0.f, 0.f, 0.f};
      a = __builtin_amdgcn_mfma_f32_16x16x32_bf16(kf0, qf0, a, 0, 0, 0);
      a = __builtin_amdgcn_mfma_f32_16x16x32_bf16(kf1, qf1, a, 0, 0, 0);
      sacc[tk] = a;
    }

    // ---- mask + per-row (lane-local) online softmax, log2 domain ----
    float sv[16];
    #pragma unroll
    for (int tk = 0; tk < 4; tk++) {
      uint32_t w = (tk < 2) ? mw.x : mw.y;
      #pragma unroll
      for (int r = 0; r < 4; r++) {
        int sh = (tk & 1) * 16 + hi*4 + r;
        sv[tk*4 + r] = ((w >> sh) & 1u) ? -1e30f : sacc[tk][r];
      }
    }
    float t8[8];
    #pragma unroll
    for (int i = 0; i < 8; i++) t8[i] = fmaxf(sv[i], sv[i+8]);
    float t4a = fmaxf(fmaxf(t8[0], t8[1]), fmaxf(t8[2], t8[3]));
    float t4b = fmaxf(fmaxf(t8[4], t8[5]), fmaxf(t8[6], t8[7]));
    float mc = fmaxf(t4a, t4b);
    mc = fmaxf(mc, __shfl_xor(mc, 16));
    mc = fmaxf(mc, __shfl_xor(mc, 32));
    float mnew = fmaxf(m_run, mc);
    float alpha = __builtin_amdgcn_exp2f(m_run - mnew);
    m_run = mnew;
    l_run *= alpha;
    #pragma unroll
    for (int i = 0; i < 16; i++) sv[i] = __builtin_amdgcn_exp2f(sv[i] - mnew);  // masked -> 0
    #pragma unroll
    for (int i = 0; i < 8; i++) t8[i] = sv[i] + sv[i+8];
    float s4a = (t8[0] + t8[1]) + (t8[2] + t8[3]);
    float s4b = (t8[4] + t8[5]) + (t8[6] + t8[7]);
    float lsum = s4a + s4b;
    lsum += __shfl_xor(lsum, 16);
    lsum += __shfl_xor(lsum, 32);
    l_run += lsum;

    // ---- rescale accO (rows q = hi*4 + r need alpha from lane hi*4+r) ----
    float af[4];
    #pragma unroll
    for (int r = 0; r < 4; r++) af[r] = __shfl(alpha, hi*4 + r);
    #pragma unroll
    for (int dn = 0; dn < 4; dn++)
      #pragma unroll
      for (int r = 0; r < 4; r++) accO[dn][r] *= af[r];

    // ---- pack P to bf16, wave-private LDS rows (no barrier needed) ----
    #pragma unroll
    for (int tk = 0; tk < 4; tk++) {
      uint2 pk;
      pk.x = pack_bf16x2(sv[tk*4+0], sv[tk*4+1]);
      pk.y = pack_bf16x2(sv[tk*4+2], sv[tk*4+3]);
      *reinterpret_cast<uint2*>(pbase + ((tk*32 + hi*8) ^ psw)) = pk;
    }
    asm volatile("s_waitcnt lgkmcnt(0)" ::: "memory");
    __builtin_amdgcn_sched_barrier(0);

    // ---- PV: accO[dn] += P(16x64) @ V^T ----
    const char* VsB = (const char*)Vs[cur];
    #pragma unroll
    for (int ks = 0; ks < 2; ks++) {
      bfrag pa = *reinterpret_cast<const bfrag*>(pbase + ((ks*64 + hi*16) ^ psw));
      #pragma unroll
      for (int dn = 0; dn < 4; dn++) {
        int vrow = dn*16 + lo;
        bfrag vf = *reinterpret_cast<const bfrag*>(VsB + vrow*128 + ((ks*64 + hi*16) ^ psw));
        accO[dn] = __builtin_amdgcn_mfma_f32_16x16x32_bf16(pa, vf, accO[dn], 0, 0, 0);
      }
    }
    __syncthreads();   // drains prefetch vmcnt + protects Ks/Vs[cur] for next-iter overwrite
  }
#undef STAGE

  // ---- finalize ----
  float linv[4];
  #pragma unroll
  for (int r = 0; r < 4; r++) {
    float lr = __shfl(l_run, hi*4 + r);
    linv[r] = (lr > 0.f) ? (1.f / lr) : 0.f;
  }
  #pragma unroll
  for (int r = 0; r < 4; r++) {
    int q = q0 + wave*16 + hi*4 + r;
    u16* orow = xout + ((size_t)b * S_ + q) * H_ + h * DK_;
    #pragma unroll
    for (int dn = 0; dn < 4; dn++)
      orow[dn*16 + lo] = f2bf(accO[dn][r] * linv[r]);
  }
}

// ---------------- launch ----------------
extern "C" void kernel_launch(void* const* d_in, const int* in_sizes, int n_in,
                              void* d_out, int out_size, void* d_ws, size_t ws_size,
                              hipStream_t stream) {
  const float* query = (const float*)d_in[0];
  const float* key_  = (const float*)d_in[1];
  const float* value = (const float*)d_in[2];
  const int*   mask  = (const int*)d_in[3];
  const float* Wq = (const float*)d_in[4];
  const float* bq = (const float*)d_in[5];
  const float* Wk = (const float*)d_in[6];
  const float* bk = (const float*)d_in[7];
  const float* Wv = (const float*)d_in[8];
  const float* bv = (const float*)d_in[9];
  const float* Wo = (const float*)d_in[10];
  const float* bo = (const float*)d_in[11];
  float* out = (float*)d_out;

  char* ws = (char*)d_ws;
  const size_t MB = 1024 * 1024;
  u16* q_act = (u16*)(ws + 0*MB);
  u16* k_act = (u16*)(ws + 16*MB);
  u16* v_act = (u16*)(ws + 32*MB);
  u16* wq_b  = (u16*)(ws + 48*MB);
  u16* wk_b  = (u16*)(ws + 50*MB);
  u16* wv_b  = (u16*)(ws + 52*MB);
  u16* wo_b  = (u16*)(ws + 54*MB);
  u16* qh    = (u16*)(ws + 56*MB);
  u16* kh    = (u16*)(ws + 72*MB);
  u16* vh    = (u16*)(ws + 88*MB);
  u16* vt    = (u16*)(ws + 104*MB);
  u16* xb    = (u16*)(ws + 120*MB);
  uint32_t* mbits = (uint32_t*)(ws + 136*MB);

  const float QSCALE = 0.125f * 1.44269504088896f;   // 1/sqrt(DK) * log2(e), folded into Wq/bq

  const int nact4 = M_ * H_ / 4;
  cvt_kernel<<<2048, 256, 0, stream>>>(query, q_act, nact4, 1.0f);
  cvt_kernel<<<2048, 256, 0, stream>>>(key_,  k_act, nact4, 1.0f);
  cvt_kernel<<<2048, 256, 0, stream>>>(value, v_act, nact4, 1.0f);
  const int nw4 = H_ * H_ / 4;
  cvt_kernel<<<1024, 256, 0, stream>>>(Wq, wq_b, nw4, QSCALE);
  cvt_kernel<<<1024, 256, 0, stream>>>(Wk, wk_b, nw4, 1.0f);
  cvt_kernel<<<1024, 256, 0, stream>>>(Wv, wv_b, nw4, 1.0f);
  cvt_kernel<<<1024, 256, 0, stream>>>(Wo, wo_b, nw4, 1.0f);
  const int nwords = B_ * S_ * S_ / 32;
  pack_mask_kernel<<<nwords/256, 256, 0, stream>>>(mask, mbits, nwords);

  dim3 gg(M_/128, H_/128);
  gemm_bt<0><<<gg, 256, 0, stream>>>(q_act, wq_b, bq, QSCALE, qh);
  gemm_bt<0><<<gg, 256, 0, stream>>>(k_act, wk_b, bk, 1.0f, kh);
  gemm_bt<0><<<gg, 256, 0, stream>>>(v_act, wv_b, bv, 1.0f, vh);
  transpose_v<<<dim3(S_/64, B_*NH_), 256, 0, stream>>>(vh, vt);
  attn_kernel<<<dim3(S_/64, B_*NH_), 256, 0, stream>>>(qh, kh, vt, mbits, xb);
  gemm_bt<1><<<gg, 256, 0, stream>>>(xb, wo_b, bo, 1.0f, out);
}